// Round 3
// baseline (147.524 us; speedup 1.0000x reference)
//
#include <hip/hip_runtime.h>

#define NROWS 100000
#define IN_DIM 512

typedef __attribute__((ext_vector_type(8))) short short8;
typedef __attribute__((ext_vector_type(4))) float f32x4;

__device__ inline unsigned short f2bf(float f) {
    union { float f; unsigned u; } v; v.f = f;
    unsigned u = v.u;
    return (unsigned short)((u + 0x7FFFu + ((u >> 16) & 1u)) >> 16);
}

// Prepack: build B-fragments (bf16) in exact MFMA lane order + fused que bias.
// B = [80 cols x 512 k]: cols 0..63 = Wv, 64..71 = Wq@Wk, 72..79 = 0.
// Bp layout: [t(5)][ks(16)][lane(64)][e(8)] bf16; col = t*16+(lane&15),
// k = ks*32 + (lane>>4)*8 + e.
__global__ void qg_prepack(const float* __restrict__ Wk, const float* __restrict__ bk,
                           const float* __restrict__ Wq, const float* __restrict__ bq,
                           const float* __restrict__ Wv,
                           unsigned short* __restrict__ Bp, float* __restrict__ qb) {
    int id = blockIdx.x * 256 + threadIdx.x;  // 0..5119
    if (id < 8) {
        float s = bq[id];
        #pragma unroll 4
        for (int j = 0; j < 100; ++j) s += Wq[id * 100 + j] * bk[j];
        qb[id] = s;
    }
    if (id >= 5120) return;
    int lane = id & 63;
    int ks = (id >> 6) & 15;
    int t = id >> 10;
    int c = t * 16 + (lane & 15);
    int kk = ks * 32 + (lane >> 4) * 8;
    short8 pk;
    #pragma unroll
    for (int e = 0; e < 8; ++e) {
        int k2 = kk + e;
        float w;
        if (c < 64) {
            w = Wv[c * IN_DIM + k2];
        } else if (c < 72) {
            float s = 0.f;
            #pragma unroll 4
            for (int j = 0; j < 100; ++j) s += Wq[(c - 64) * 100 + j] * Wk[j * IN_DIM + k2];
            w = s;
        } else {
            w = 0.f;
        }
        pk[e] = (short)f2bf(w);
    }
    ((short8*)Bp)[id] = pk;
}

// Main: 128 threads = 2 fully-independent waves, 16 rows/wave, NO barriers.
// A: 3-deep register prefetch from global; B: 2-deep from L2-resident Bp.
__global__ __launch_bounds__(128, 4) void qg_main(const float* __restrict__ x,
                                                  const float* __restrict__ bv,
                                                  const unsigned short* __restrict__ Bp,
                                                  const float* __restrict__ qb,
                                                  float* __restrict__ out) {
    __shared__ float vlds[2][16][68];
    __shared__ float wlds[2][16][8];
    const int tid = threadIdx.x;
    const int w = tid >> 6;
    const int lane = tid & 63;
    const int g = lane >> 4;       // k sub-block (k = g*8+e within a 32-K MFMA step)
    const int cl = lane & 15;      // A row within wave-tile / B col within tile
    const int rowbase = blockIdx.x * 32 + w * 16;   // grid 3125 * 32 = 100000 exact

    const float* ap = x + (size_t)(rowbase + cl) * IN_DIM + g * 8;
    const short8* bp8 = (const short8*)Bp + lane;

    f32x4 acc[5];
    #pragma unroll
    for (int t = 0; t < 5; ++t) acc[t] = (f32x4){0.f, 0.f, 0.f, 0.f};

    float4 A[3][2];
    short8 B[2][5];

    // Prologue: 3 A-steps, 2 B-steps in flight.
    #pragma unroll
    for (int p = 0; p < 3; ++p) {
        A[p][0] = *(const float4*)(ap + p * 32);
        A[p][1] = *(const float4*)(ap + p * 32 + 4);
    }
    #pragma unroll
    for (int p = 0; p < 2; ++p)
        #pragma unroll
        for (int t = 0; t < 5; ++t)
            B[p][t] = bp8[(t * 16 + p) * 64];

    #pragma unroll
    for (int s = 0; s < 16; ++s) {
        const int ai = s % 3, bi = s % 2;
        float4 f0 = A[ai][0];
        float4 f1 = A[ai][1];
        short8 af;
        af[0] = (short)f2bf(f0.x); af[1] = (short)f2bf(f0.y);
        af[2] = (short)f2bf(f0.z); af[3] = (short)f2bf(f0.w);
        af[4] = (short)f2bf(f1.x); af[5] = (short)f2bf(f1.y);
        af[6] = (short)f2bf(f1.z); af[7] = (short)f2bf(f1.w);
        if (s + 3 < 16) {
            A[ai][0] = *(const float4*)(ap + (s + 3) * 32);
            A[ai][1] = *(const float4*)(ap + (s + 3) * 32 + 4);
        }
        #pragma unroll
        for (int t = 0; t < 5; ++t)
            acc[t] = __builtin_amdgcn_mfma_f32_16x16x32_bf16(af, B[bi][t], acc[t], 0, 0, 0);
        if (s + 2 < 16) {
            #pragma unroll
            for (int t = 0; t < 5; ++t)
                B[bi][t] = bp8[(t * 16 + s + 2) * 64];
        }
    }

    // ---- Per-wave epilogue (intra-wave lockstep; lgkmcnt ordering only) ----
    // C layout: col = lane&15, row = (lane>>4)*4 + reg  (verified m89).
    #pragma unroll
    for (int t = 0; t < 4; ++t) {
        float b = bv[t * 16 + cl];
        #pragma unroll
        for (int r = 0; r < 4; ++r)
            vlds[w][g * 4 + r][t * 16 + cl] = acc[t][r] + b;
    }
    if (cl < 8) {
        float b = qb[cl];
        #pragma unroll
        for (int r = 0; r < 4; ++r)
            wlds[w][g * 4 + r][cl] = acc[4][r] + b;
    }
    asm volatile("s_waitcnt lgkmcnt(0)" ::: "memory");

    // Softmax over the 8 que values: lanes 0..15 each own one row.
    if (lane < 16) {
        float q[8];
        float m = -1e30f;
        #pragma unroll
        for (int k = 0; k < 8; ++k) { q[k] = wlds[w][lane][k]; m = fmaxf(m, q[k]); }
        float ssum = 0.f;
        #pragma unroll
        for (int k = 0; k < 8; ++k) { q[k] = __expf(q[k] - m); ssum += q[k]; }
        float inv = 1.f / ssum;
        #pragma unroll
        for (int k = 0; k < 8; ++k) wlds[w][lane][k] = q[k] * inv;
    }
    asm volatile("s_waitcnt lgkmcnt(0)" ::: "memory");

    // Coalesced output: out[row][k][v] = w[k] * val[v];  per-instr = contiguous 1 KB.
    float4* outp = (float4*)out + (size_t)rowbase * 128;
    #pragma unroll
    for (int it = 0; it < 32; ++it) {
        int idx = it * 64 + lane;
        int row = idx >> 7;             // 0..15
        int j = idx & 127;              // float4 index within 512-float out row
        float wgt = wlds[w][row][j >> 4];
        float4 vv = *(const float4*)&vlds[w][row][(j & 15) * 4];
        float4 o;
        o.x = wgt * vv.x; o.y = wgt * vv.y; o.z = wgt * vv.z; o.w = wgt * vv.w;
        outp[(size_t)row * 128 + j] = o;
    }
}

extern "C" void kernel_launch(void* const* d_in, const int* in_sizes, int n_in,
                              void* d_out, int out_size, void* d_ws, size_t ws_size,
                              hipStream_t stream) {
    const float* x  = (const float*)d_in[0];
    const float* Wk = (const float*)d_in[1];
    const float* bk = (const float*)d_in[2];
    const float* Wq = (const float*)d_in[3];
    const float* bq = (const float*)d_in[4];
    const float* Wv = (const float*)d_in[5];
    const float* bv = (const float*)d_in[6];
    float* out = (float*)d_out;

    unsigned short* Bp = (unsigned short*)d_ws;          // 5*16*64*8 bf16 = 81920 B
    float* qb = (float*)((char*)d_ws + 81920);           // 8 floats

    qg_prepack<<<20, 256, 0, stream>>>(Wk, bk, Wq, bq, Wv, Bp, qb);
    qg_main<<<3125, 128, 0, stream>>>(x, bv, Bp, qb, out);
}

// Round 5
// 107.060 us; speedup vs baseline: 1.3780x; 1.3780x over previous
//
#include <hip/hip_runtime.h>

#define NROWS 100000
#define IN_DIM 512

typedef __attribute__((ext_vector_type(8))) short short8;
typedef __attribute__((ext_vector_type(4))) float f32x4;

__device__ inline unsigned short f2bf(float f) {
    union { float f; unsigned u; } v; v.f = f;
    unsigned u = v.u;
    return (unsigned short)((u + 0x7FFFu + ((u >> 16) & 1u)) >> 16);
}

// Prepack: build B-fragments (bf16) in exact MFMA lane order + fused que bias.
// B = [80 cols x 512 k]: cols 0..63 = Wv, 64..71 = Wq@Wk, 72..79 = 0.
// Bp layout: [t(5)][ks(16)][lane(64)][e(8)] bf16; col = t*16+(lane&15),
// k = ks*32 + (lane>>4)*8 + e.
__global__ void qg_prepack(const float* __restrict__ Wk, const float* __restrict__ bk,
                           const float* __restrict__ Wq, const float* __restrict__ bq,
                           const float* __restrict__ Wv,
                           unsigned short* __restrict__ Bp, float* __restrict__ qb) {
    int id = blockIdx.x * 256 + threadIdx.x;  // 0..5119
    if (id < 8) {
        float s = bq[id];
        #pragma unroll 4
        for (int j = 0; j < 100; ++j) s += Wq[id * 100 + j] * bk[j];
        qb[id] = s;
    }
    if (id >= 5120) return;
    int lane = id & 63;
    int ks = (id >> 6) & 15;
    int t = id >> 10;
    int c = t * 16 + (lane & 15);
    int kk = ks * 32 + (lane >> 4) * 8;
    short8 pk;
    #pragma unroll
    for (int e = 0; e < 8; ++e) {
        int k2 = kk + e;
        float w;
        if (c < 64) {
            w = Wv[c * IN_DIM + k2];
        } else if (c < 72) {
            float s = 0.f;
            #pragma unroll 4
            for (int j = 0; j < 100; ++j) s += Wq[(c - 64) * 100 + j] * Wk[j * IN_DIM + k2];
            w = s;
        } else {
            w = 0.f;
        }
        pk[e] = (short)f2bf(w);
    }
    ((short8*)Bp)[id] = pk;
}

// Main: 128 threads = 2 fully-independent waves, 16 rows/wave, NO barriers.
// A: 3-deep register prefetch from global; B: 2-deep from L2-resident Bp.
// Out stores are NONTEMPORAL: out is write-once, keep it out of L2/L3 so x
// stays cache-resident.
__global__ __launch_bounds__(128, 4) void qg_main(const float* __restrict__ x,
                                                  const float* __restrict__ bv,
                                                  const unsigned short* __restrict__ Bp,
                                                  const float* __restrict__ qb,
                                                  float* __restrict__ out) {
    __shared__ float vlds[2][16][68];
    __shared__ float wlds[2][16][8];
    const int tid = threadIdx.x;
    const int w = tid >> 6;
    const int lane = tid & 63;
    const int g = lane >> 4;       // k sub-block (k = g*8+e within a 32-K MFMA step)
    const int cl = lane & 15;      // A row within wave-tile / B col within tile
    const int rowbase = blockIdx.x * 32 + w * 16;   // grid 3125 * 32 = 100000 exact

    const float* ap = x + (size_t)(rowbase + cl) * IN_DIM + g * 8;
    const short8* bp8 = (const short8*)Bp + lane;

    f32x4 acc[5];
    #pragma unroll
    for (int t = 0; t < 5; ++t) acc[t] = (f32x4){0.f, 0.f, 0.f, 0.f};

    float4 A[3][2];
    short8 B[2][5];

    // Prologue: 3 A-steps, 2 B-steps in flight.
    #pragma unroll
    for (int p = 0; p < 3; ++p) {
        A[p][0] = *(const float4*)(ap + p * 32);
        A[p][1] = *(const float4*)(ap + p * 32 + 4);
    }
    #pragma unroll
    for (int p = 0; p < 2; ++p)
        #pragma unroll
        for (int t = 0; t < 5; ++t)
            B[p][t] = bp8[(t * 16 + p) * 64];

    #pragma unroll
    for (int s = 0; s < 16; ++s) {
        const int ai = s % 3, bi = s % 2;
        float4 f0 = A[ai][0];
        float4 f1 = A[ai][1];
        short8 af;
        af[0] = (short)f2bf(f0.x); af[1] = (short)f2bf(f0.y);
        af[2] = (short)f2bf(f0.z); af[3] = (short)f2bf(f0.w);
        af[4] = (short)f2bf(f1.x); af[5] = (short)f2bf(f1.y);
        af[6] = (short)f2bf(f1.z); af[7] = (short)f2bf(f1.w);
        if (s + 3 < 16) {
            A[ai][0] = *(const float4*)(ap + (s + 3) * 32);
            A[ai][1] = *(const float4*)(ap + (s + 3) * 32 + 4);
        }
        #pragma unroll
        for (int t = 0; t < 5; ++t)
            acc[t] = __builtin_amdgcn_mfma_f32_16x16x32_bf16(af, B[bi][t], acc[t], 0, 0, 0);
        if (s + 2 < 16) {
            #pragma unroll
            for (int t = 0; t < 5; ++t)
                B[bi][t] = bp8[(t * 16 + s + 2) * 64];
        }
    }

    // ---- Per-wave epilogue (intra-wave lockstep; lgkmcnt ordering only) ----
    // C layout: col = lane&15, row = (lane>>4)*4 + reg  (verified m89).
    #pragma unroll
    for (int t = 0; t < 4; ++t) {
        float b = bv[t * 16 + cl];
        #pragma unroll
        for (int r = 0; r < 4; ++r)
            vlds[w][g * 4 + r][t * 16 + cl] = acc[t][r] + b;
    }
    if (cl < 8) {
        float b = qb[cl];
        #pragma unroll
        for (int r = 0; r < 4; ++r)
            wlds[w][g * 4 + r][cl] = acc[4][r] + b;
    }
    asm volatile("s_waitcnt lgkmcnt(0)" ::: "memory");

    // Softmax over the 8 que values: lanes 0..15 each own one row.
    if (lane < 16) {
        float q[8];
        float m = -1e30f;
        #pragma unroll
        for (int k = 0; k < 8; ++k) { q[k] = wlds[w][lane][k]; m = fmaxf(m, q[k]); }
        float ssum = 0.f;
        #pragma unroll
        for (int k = 0; k < 8; ++k) { q[k] = __expf(q[k] - m); ssum += q[k]; }
        float inv = 1.f / ssum;
        #pragma unroll
        for (int k = 0; k < 8; ++k) wlds[w][lane][k] = q[k] * inv;
    }
    asm volatile("s_waitcnt lgkmcnt(0)" ::: "memory");

    // Coalesced NONTEMPORAL output: out[row][k][v] = w[k] * val[v];
    // per-instr = contiguous 1 KB, streams past L2/L3.
    f32x4* outp = (f32x4*)out + (size_t)rowbase * 128;
    #pragma unroll
    for (int it = 0; it < 32; ++it) {
        int idx = it * 64 + lane;
        int row = idx >> 7;             // 0..15
        int j = idx & 127;              // float4 index within 512-float out row
        float wgt = wlds[w][row][j >> 4];
        float4 vv = *(const float4*)&vlds[w][row][(j & 15) * 4];
        f32x4 o;
        o[0] = wgt * vv.x; o[1] = wgt * vv.y; o[2] = wgt * vv.z; o[3] = wgt * vv.w;
        __builtin_nontemporal_store(o, &outp[(size_t)row * 128 + j]);
    }
}

extern "C" void kernel_launch(void* const* d_in, const int* in_sizes, int n_in,
                              void* d_out, int out_size, void* d_ws, size_t ws_size,
                              hipStream_t stream) {
    const float* x  = (const float*)d_in[0];
    const float* Wk = (const float*)d_in[1];
    const float* bk = (const float*)d_in[2];
    const float* Wq = (const float*)d_in[3];
    const float* bq = (const float*)d_in[4];
    const float* Wv = (const float*)d_in[5];
    const float* bv = (const float*)d_in[6];
    float* out = (float*)d_out;

    unsigned short* Bp = (unsigned short*)d_ws;          // 5*16*64*8 bf16 = 81920 B
    float* qb = (float*)((char*)d_ws + 81920);           // 8 floats

    qg_prepack<<<20, 256, 0, stream>>>(Wk, bk, Wq, bq, Wv, Bp, qb);
    qg_main<<<3125, 128, 0, stream>>>(x, bv, Bp, qb, out);
}